// Round 7
// baseline (67.574 us; speedup 1.0000x reference)
//
#include <hip/hip_runtime.h>
#include <hip/hip_bf16.h>

// GraphAttentionLayer collapse: out[b,i,o] = (S_mask[b,i,o] < 0) ? 1 : 0,
// S_mask = sum_{adj[i,j]==0} hW[b,j,o]  (|9e15*S_mask| >> |softmax term| => sigmoid saturates).
// Exact i8 MFMA path:
//   q = rint(hW*2^16) = d0 + 256*d1 + 65536*d2, balanced digits in [-128,127] (exact i8).
//   mask bit 0/1 exact i8; i32 MFMA accumulation exact.
//   S = c0 + 256*c1 + 65536*c2 (f64, exact integers). |S| > 2048 => sign reliable;
//   else exact f64 recompute in fixup kernel (~50 outputs expected).
// Round-7: gemm drops LDS staging + ALL k-loop barriers (waves read disjoint B slices
// -> staging had zero reuse); depth-2 register pipeline straight from L2.
// repack fused into hw (digit word assembled via 4-row LDS exchange).

#define GN 4096
#define GB 4
#define FIN 128
#define FOUT 64
#define FLAG_CAP 65536

typedef int i32x4 __attribute__((ext_vector_type(4)));
typedef unsigned int uint32x4 __attribute__((ext_vector_type(4)));
typedef float f32x4 __attribute__((ext_vector_type(4)));

// ---- kernel 1: adj -> transposed bitmask tmask[(rt*64+s)*64 + lane] (u64) ----
// bit (r*16 + jj) of tmask[rt*64+s][l] = (adj[rt*64 + r*16 + (l&15)][s*64 + (l>>4)*16 + jj] == 0)
__global__ __launch_bounds__(256) void pack_kernel(const int* __restrict__ adj,
                                                   unsigned long long* __restrict__ tmask,
                                                   unsigned int* __restrict__ counter) {
    if (blockIdx.x == 0 && threadIdx.x == 0) *counter = 0;
    int wid = blockIdx.x * 4 + (threadIdx.x >> 6);
    int lane = threadIdx.x & 63;
    int rt = wid >> 6, s = wid & 63;
    int row16 = lane & 15, g = lane >> 4;
    const int* base = adj + (size_t)(rt * 64 + row16) * GN + s * 64 + g * 16;
    unsigned long long res = 0ull;
#pragma unroll
    for (int r = 0; r < 4; ++r) {
        const i32x4* p = (const i32x4*)(base + (size_t)r * 16 * GN);
        unsigned int b16 = 0;
#pragma unroll
        for (int q = 0; q < 4; ++q) {
            i32x4 v = p[q];
            b16 |= (v.x == 0 ? 1u : 0u) << (q * 4);
            b16 |= (v.y == 0 ? 2u : 0u) << (q * 4);
            b16 |= (v.z == 0 ? 4u : 0u) << (q * 4);
            b16 |= (v.w == 0 ? 8u : 0u) << (q * 4);
        }
        res |= (unsigned long long)b16 << (r * 16);
    }
    tmask[(size_t)wid * 64 + lane] = res;
}

// ---- kernel 2: hW = h @ W (f64) + fused digit-plane packing ----
// block = 4 consecutive rows (blockIdx = b*1024 + q4, rows j = q4*4 .. q4*4+3).
// After the dot product, the 4 rows' packed digits are exchanged through LDS and
// 3 of the 4 thread-groups store one u32 digit-word each (plane = grp) to Bp:
// Bp[(b*64+p)*12288 + pl*4096 + cg*1024 + g*256 + col16*16 + qr*4], byte rr = digit
// pl of row p*64+g*16+qr*4+rr, col o=cg*16+col16  (identical layout to verified repack).
__global__ __launch_bounds__(256) void hwrepack_kernel(const float* __restrict__ h,
                                                       const float* __restrict__ W,
                                                       double* __restrict__ hW,
                                                       unsigned char* __restrict__ Bp) {
    const int grp = threadIdx.x >> 6;
    const int o = threadIdx.x & 63;
    const int b = blockIdx.x >> 10, q4 = blockIdx.x & 1023;
    __shared__ float hs[4][FIN];
    __shared__ unsigned int dg[4][64];
    {
        const f32x4* src = (const f32x4*)(h + ((size_t)b * GN + q4 * 4) * FIN);
        f32x4* dst = (f32x4*)&hs[0][0];
        if (threadIdx.x < 128) dst[threadIdx.x] = src[threadIdx.x];
    }
    __syncthreads();
    double a0 = 0, a1 = 0, a2 = 0, a3 = 0;
#pragma unroll
    for (int i = 0; i < FIN; i += 4) {
        a0 = fma((double)hs[grp][i],     (double)W[i * FOUT + o],       a0);
        a1 = fma((double)hs[grp][i + 1], (double)W[(i + 1) * FOUT + o], a1);
        a2 = fma((double)hs[grp][i + 2], (double)W[(i + 2) * FOUT + o], a2);
        a3 = fma((double)hs[grp][i + 3], (double)W[(i + 3) * FOUT + o], a3);
    }
    double acc = (a0 + a1) + (a2 + a3);
    hW[((size_t)b * GN + q4 * 4 + grp) * FOUT + o] = acc;

    int qi = (int)llrint(acc * 65536.0);
    int d0 = ((qi + 128) & 255) - 128; qi = (qi - d0) >> 8;
    int d1 = ((qi + 128) & 255) - 128; qi = (qi - d1) >> 8;  // qi now = d2
    dg[grp][o] = (unsigned int)(d0 & 255) | ((unsigned int)(d1 & 255) << 8)
               | ((unsigned int)(qi & 255) << 16);
    __syncthreads();
    if (grp < 3) {   // grp = digit plane
        unsigned int w = 0;
#pragma unroll
        for (int rr = 0; rr < 4; ++rr)
            w |= ((dg[rr][o] >> (grp * 8)) & 255u) << (rr * 8);
        const int p = q4 >> 4, g = (q4 >> 2) & 3, qr = q4 & 3;
        const int cg = o >> 4, col16 = o & 15;
        *(unsigned int*)(Bp + ((size_t)b * 64 + p) * 12288 + grp * 4096
                         + cg * 1024 + g * 256 + col16 * 16 + qr * 4) = w;
    }
}

// ---- kernel 3: exact i8-MFMA masked-sum GEMM, barrier-free register pipeline ----
// 8 waves read DISJOINT B slices (cg = 16 cols, kg = K-chunk) -> no LDS staging,
// no k-loop barriers. Depth-2 named register sets (A/B), L2-resident Bp.
__global__ __launch_bounds__(512, 1) void gemm_kernel(const unsigned char* __restrict__ Bp,
                                                      const unsigned long long* __restrict__ tmask,
                                                      float* __restrict__ out,
                                                      unsigned int* __restrict__ flags,
                                                      unsigned int* __restrict__ counter) {
    __shared__ __align__(16) unsigned char lds[49152];   // kg-merge only
    const int tid = threadIdx.x, lane = tid & 63, wv = tid >> 6;
    const int cg = wv & 3, kg = wv >> 2;
    const int rt = (int)blockIdx.x >> 2, b = (int)blockIdx.x & 3;

    const unsigned char* bptr = Bp + (size_t)b * 786432 + kg * 12288 + cg * 1024 + lane * 16;
    const unsigned long long* mptr = tmask + (size_t)rt * 4096 + kg * 64 + lane;

    i32x4 acc[4][3];
#pragma unroll
    for (int r = 0; r < 4; ++r)
#pragma unroll
        for (int pl = 0; pl < 3; ++pl) {
            i32x4 z = {0, 0, 0, 0};
            acc[r][pl] = z;
        }

    // depth-2 prologue
    i32x4 ba0 = *(const i32x4*)(bptr);
    i32x4 ba1 = *(const i32x4*)(bptr + 4096);
    i32x4 ba2 = *(const i32x4*)(bptr + 8192);
    unsigned long long ma = mptr[0];
    i32x4 bb0 = *(const i32x4*)(bptr + 24576);
    i32x4 bb1 = *(const i32x4*)(bptr + 24576 + 4096);
    i32x4 bb2 = *(const i32x4*)(bptr + 24576 + 8192);
    unsigned long long mb = mptr[128];

    auto dostep = [&](unsigned long long mw, i32x4 v0, i32x4 v1, i32x4 v2) {
        const unsigned int mlo = (unsigned int)mw, mhi = (unsigned int)(mw >> 32);
#pragma unroll
        for (int r = 0; r < 4; ++r) {
            unsigned int half = (r >> 1) ? mhi : mlo;
            unsigned int w16 = (r & 1) ? (half >> 16) : (half & 0xFFFFu);
            uint32x4 u;
#pragma unroll
            for (int q = 0; q < 4; ++q)
                u[q] = (((w16 >> (4 * q)) & 0xFu) * 0x00204081u) & 0x01010101u;
            i32x4 af = __builtin_bit_cast(i32x4, u);
            acc[r][0] = __builtin_amdgcn_mfma_i32_16x16x64_i8(af, v0, acc[r][0], 0, 0, 0);
            acc[r][1] = __builtin_amdgcn_mfma_i32_16x16x64_i8(af, v1, acc[r][1], 0, 0, 0);
            acc[r][2] = __builtin_amdgcn_mfma_i32_16x16x64_i8(af, v2, acc[r][2], 0, 0, 0);
        }
    };

    for (int T = 0; T < 32; T += 2) {
        dostep(ma, ba0, ba1, ba2);
        if (T + 2 < 32) {
            const unsigned char* g2 = bptr + (size_t)(T + 2) * 24576;
            ba0 = *(const i32x4*)(g2);
            ba1 = *(const i32x4*)(g2 + 4096);
            ba2 = *(const i32x4*)(g2 + 8192);
            ma = mptr[(size_t)(T + 2) * 128];
        }
        dostep(mb, bb0, bb1, bb2);
        if (T + 3 < 32) {
            const unsigned char* g3 = bptr + (size_t)(T + 3) * 24576;
            bb0 = *(const i32x4*)(g3);
            bb1 = *(const i32x4*)(g3 + 4096);
            bb2 = *(const i32x4*)(g3 + 8192);
            mb = mptr[(size_t)(T + 3) * 128];
        }
    }

    // merge kg=1 partials into kg=0 via LDS
    __syncthreads();
    if (kg == 1) {
        unsigned char* dst = lds + cg * 12288 + lane * 192;
#pragma unroll
        for (int r = 0; r < 4; ++r)
#pragma unroll
            for (int pl = 0; pl < 3; ++pl)
                *(i32x4*)(dst + (r * 3 + pl) * 16) = acc[r][pl];
    }
    __syncthreads();
    if (kg == 0) {
        const unsigned char* s2 = lds + cg * 12288 + lane * 192;
#pragma unroll
        for (int r = 0; r < 4; ++r)
#pragma unroll
            for (int pl = 0; pl < 3; ++pl) {
                i32x4 v = *(const i32x4*)(s2 + (r * 3 + pl) * 16);
#pragma unroll
                for (int q = 0; q < 4; ++q) acc[r][pl][q] += v[q];
            }

        const int o = cg * 16 + (lane & 15);
#pragma unroll
        for (int r = 0; r < 4; ++r) {
#pragma unroll
            for (int q = 0; q < 4; ++q) {
                double S = (double)acc[r][0][q] + 256.0 * (double)acc[r][1][q]
                         + 65536.0 * (double)acc[r][2][q];     // exact integer
                int i = rt * 64 + r * 16 + (lane >> 4) * 4 + q;  // C/D row map (m89)
                size_t oi = ((size_t)b * GN + i) * FOUT + o;
                out[oi] = S < 0.0 ? 1.0f : 0.0f;
                if (fabs(S) <= 2048.0) {
                    unsigned int idx = atomicAdd(counter, 1u);
                    if (idx < FLAG_CAP) flags[idx] = (unsigned int)oi;
                }
            }
        }
    }
}

// ---- kernel 4: exact f64 recompute for borderline outputs, one block per item ----
__global__ __launch_bounds__(256) void fixup_kernel(const int* __restrict__ adj,
                                                    const double* __restrict__ hW,
                                                    const unsigned int* __restrict__ counter,
                                                    const unsigned int* __restrict__ flags,
                                                    float* __restrict__ out) {
    __shared__ double red[4];
    unsigned int cnt = *counter;
    if (cnt > FLAG_CAP) cnt = FLAG_CAP;
    for (unsigned int f = blockIdx.x; f < cnt; f += gridDim.x) {
        unsigned int e = flags[f];
        int o = e & 63;
        int i = (e >> 6) & 4095;
        int b = (int)(e >> 18);
        double s = 0.0;
#pragma unroll
        for (int it = 0; it < 16; ++it) {
            int j = it * 256 + threadIdx.x;
            int av = adj[(size_t)i * GN + j];
            double v = hW[((size_t)b * GN + j) * FOUT + o];
            s += (av == 0) ? v : 0.0;
        }
#pragma unroll
        for (int d = 32; d >= 1; d >>= 1) s += __shfl_down(s, d, 64);
        if ((threadIdx.x & 63) == 0) red[threadIdx.x >> 6] = s;
        __syncthreads();
        if (threadIdx.x == 0) {
            double tot = (red[0] + red[1]) + (red[2] + red[3]);
            out[e] = tot < 0.0 ? 1.0f : 0.0f;
        }
        __syncthreads();   // red[] reused next item
    }
}

extern "C" void kernel_launch(void* const* d_in, const int* in_sizes, int n_in,
                              void* d_out, int out_size, void* d_ws, size_t ws_size,
                              hipStream_t stream) {
    const float* h   = (const float*)d_in[0];   // [4,4096,128]
    const int*   adj = (const int*)d_in[1];     // [4096,4096]
    const float* W   = (const float*)d_in[2];   // [128,64]
    float* out = (float*)d_out;                 // [4,4096,64] f32

    char* ws = (char*)d_ws;
    double* hW                = (double*)ws;                          // 8 MB @ 0
    unsigned char* Bp         = (unsigned char*)(ws + 8388608);       // 3 MB @ 8M
    unsigned long long* tmask = (unsigned long long*)(ws + 12582912); // 2 MB @ 12M
    unsigned int* counter     = (unsigned int*)(ws + 16777216);       // @ 16M
    unsigned int* flags       = (unsigned int*)(ws + 16777472);       // 256 KB

    pack_kernel<<<1024, 256, 0, stream>>>(adj, tmask, counter);
    hwrepack_kernel<<<4096, 256, 0, stream>>>(h, W, hW, Bp);  // 4096 blocks (4 rows each)
    gemm_kernel<<<256, 512, 0, stream>>>(Bp, tmask, out, flags, counter);
    fixup_kernel<<<128, 256, 0, stream>>>(adj, hW, counter, flags, out);
}

// Round 8
// 61.794 us; speedup vs baseline: 1.0935x; 1.0935x over previous
//
#include <hip/hip_runtime.h>
#include <hip/hip_bf16.h>

// GraphAttentionLayer collapse: out[b,i,o] = (S_mask[b,i,o] < 0) ? 1 : 0,
// S_mask = sum_{adj[i,j]==0} hW[b,j,o]  (|9e15*S_mask| >> |softmax term| => sigmoid saturates).
// Exact i8 MFMA path:
//   q = rint(hW*2^16) = d0 + 256*d1 + 65536*d2, balanced digits in [-128,127] (exact i8).
//   mask bit 0/1 exact i8; i32 MFMA accumulation exact.
//   S = c0 + 256*c1 + 65536*c2 (f64, exact integers). |S| > 2048 => sign reliable;
//   else exact f64 recompute, now done IN-BLOCK (self-fixup).
// Round-8: 2 kernels total. front = pack|hwrepack fused (independent, branch on block).
// gemm self-fixes borderline outputs (LDS flag list, tmask-driven exact f64 resum),
// eliminating the flags/counter globals and two kernel launches.

#define GN 4096
#define GB 4
#define FIN 128
#define FOUT 64

typedef int i32x4 __attribute__((ext_vector_type(4)));
typedef unsigned int uint32x4 __attribute__((ext_vector_type(4)));
typedef float f32x4 __attribute__((ext_vector_type(4)));

// ---- kernel 1: fused [pack: adj -> tmask] | [hwrepack: h@W -> hW + Bp digit planes] ----
// pack (blocks 0..1023): bit (r*16+jj) of tmask[rt*64+s][l] =
//   (adj[rt*64 + r*16 + (l&15)][s*64 + (l>>4)*16 + jj] == 0)
// hwrepack (blocks 1024..5119): 4 rows per block; digits exchanged via LDS; layout
//   Bp[(b*64+p)*12288 + pl*4096 + cg*1024 + g*256 + col16*16 + qr*4] (verified r7).
__global__ __launch_bounds__(256) void front_kernel(const int* __restrict__ adj,
                                                    const float* __restrict__ h,
                                                    const float* __restrict__ W,
                                                    unsigned long long* __restrict__ tmask,
                                                    double* __restrict__ hW,
                                                    unsigned char* __restrict__ Bp) {
    __shared__ float hs[4][FIN];
    __shared__ unsigned int dg[4][64];

    if (blockIdx.x < 1024) {
        // ---------------- pack ----------------
        int wid = blockIdx.x * 4 + (threadIdx.x >> 6);
        int lane = threadIdx.x & 63;
        int rt = wid >> 6, s = wid & 63;
        int row16 = lane & 15, g = lane >> 4;
        const int* base = adj + (size_t)(rt * 64 + row16) * GN + s * 64 + g * 16;
        unsigned long long res = 0ull;
#pragma unroll
        for (int r = 0; r < 4; ++r) {
            const i32x4* p = (const i32x4*)(base + (size_t)r * 16 * GN);
            unsigned int b16 = 0;
#pragma unroll
            for (int q = 0; q < 4; ++q) {
                i32x4 v = p[q];
                b16 |= (v.x == 0 ? 1u : 0u) << (q * 4);
                b16 |= (v.y == 0 ? 2u : 0u) << (q * 4);
                b16 |= (v.z == 0 ? 4u : 0u) << (q * 4);
                b16 |= (v.w == 0 ? 8u : 0u) << (q * 4);
            }
            res |= (unsigned long long)b16 << (r * 16);
        }
        tmask[(size_t)wid * 64 + lane] = res;
    } else {
        // ---------------- hwrepack ----------------
        const int bx = blockIdx.x - 1024;
        const int grp = threadIdx.x >> 6;
        const int o = threadIdx.x & 63;
        const int b = bx >> 10, q4 = bx & 1023;
        {
            const f32x4* src = (const f32x4*)(h + ((size_t)b * GN + q4 * 4) * FIN);
            f32x4* dst = (f32x4*)&hs[0][0];
            if (threadIdx.x < 128) dst[threadIdx.x] = src[threadIdx.x];
        }
        __syncthreads();
        double a0 = 0, a1 = 0, a2 = 0, a3 = 0;
#pragma unroll
        for (int i = 0; i < FIN; i += 4) {
            a0 = fma((double)hs[grp][i],     (double)W[i * FOUT + o],       a0);
            a1 = fma((double)hs[grp][i + 1], (double)W[(i + 1) * FOUT + o], a1);
            a2 = fma((double)hs[grp][i + 2], (double)W[(i + 2) * FOUT + o], a2);
            a3 = fma((double)hs[grp][i + 3], (double)W[(i + 3) * FOUT + o], a3);
        }
        double acc = (a0 + a1) + (a2 + a3);
        hW[((size_t)b * GN + q4 * 4 + grp) * FOUT + o] = acc;

        int qi = (int)llrint(acc * 65536.0);
        int d0 = ((qi + 128) & 255) - 128; qi = (qi - d0) >> 8;
        int d1 = ((qi + 128) & 255) - 128; qi = (qi - d1) >> 8;  // qi now = d2
        dg[grp][o] = (unsigned int)(d0 & 255) | ((unsigned int)(d1 & 255) << 8)
                   | ((unsigned int)(qi & 255) << 16);
        __syncthreads();
        if (grp < 3) {   // grp = digit plane
            unsigned int w = 0;
#pragma unroll
            for (int rr = 0; rr < 4; ++rr)
                w |= ((dg[rr][o] >> (grp * 8)) & 255u) << (rr * 8);
            const int p = q4 >> 4, g = (q4 >> 2) & 3, qr = q4 & 3;
            const int cg = o >> 4, col16 = o & 15;
            *(unsigned int*)(Bp + ((size_t)b * 64 + p) * 12288 + grp * 4096
                             + cg * 1024 + g * 256 + col16 * 16 + qr * 4) = w;
        }
    }
}

// ---- kernel 2: exact i8-MFMA masked-sum GEMM + in-block exact fixup ----
// 8 waves read DISJOINT B slices (cg = 16 cols, kg = K-chunk): register pipeline,
// no k-loop barriers. Borderline outputs (|S|<=2048) collected in LDS, recomputed
// exactly in f64 by the whole block from tmask + hW after the epilogue.
__global__ __launch_bounds__(512, 1) void gemm_kernel(const unsigned char* __restrict__ Bp,
                                                      const unsigned long long* __restrict__ tmask,
                                                      const double* __restrict__ hW,
                                                      float* __restrict__ out) {
    __shared__ __align__(16) unsigned char lds[49152];   // kg-merge
    __shared__ unsigned int nflag;
    __shared__ unsigned int flagbuf[128];
    __shared__ double fred[8];

    const int tid = threadIdx.x, lane = tid & 63, wv = tid >> 6;
    const int cg = wv & 3, kg = wv >> 2;
    const int rt = (int)blockIdx.x >> 2, b = (int)blockIdx.x & 3;
    if (tid == 0) nflag = 0;

    const unsigned char* bptr = Bp + (size_t)b * 786432 + kg * 12288 + cg * 1024 + lane * 16;
    const unsigned long long* mptr = tmask + (size_t)rt * 4096 + kg * 64 + lane;

    i32x4 acc[4][3];
#pragma unroll
    for (int r = 0; r < 4; ++r)
#pragma unroll
        for (int pl = 0; pl < 3; ++pl) {
            i32x4 z = {0, 0, 0, 0};
            acc[r][pl] = z;
        }

    // depth-2 register pipeline
    i32x4 ba0 = *(const i32x4*)(bptr);
    i32x4 ba1 = *(const i32x4*)(bptr + 4096);
    i32x4 ba2 = *(const i32x4*)(bptr + 8192);
    unsigned long long ma = mptr[0];
    i32x4 bb0 = *(const i32x4*)(bptr + 24576);
    i32x4 bb1 = *(const i32x4*)(bptr + 24576 + 4096);
    i32x4 bb2 = *(const i32x4*)(bptr + 24576 + 8192);
    unsigned long long mb = mptr[128];

    auto dostep = [&](unsigned long long mw, i32x4 v0, i32x4 v1, i32x4 v2) {
        const unsigned int mlo = (unsigned int)mw, mhi = (unsigned int)(mw >> 32);
#pragma unroll
        for (int r = 0; r < 4; ++r) {
            unsigned int half = (r >> 1) ? mhi : mlo;
            unsigned int w16 = (r & 1) ? (half >> 16) : (half & 0xFFFFu);
            uint32x4 u;
#pragma unroll
            for (int q = 0; q < 4; ++q)
                u[q] = (((w16 >> (4 * q)) & 0xFu) * 0x00204081u) & 0x01010101u;
            i32x4 af = __builtin_bit_cast(i32x4, u);
            acc[r][0] = __builtin_amdgcn_mfma_i32_16x16x64_i8(af, v0, acc[r][0], 0, 0, 0);
            acc[r][1] = __builtin_amdgcn_mfma_i32_16x16x64_i8(af, v1, acc[r][1], 0, 0, 0);
            acc[r][2] = __builtin_amdgcn_mfma_i32_16x16x64_i8(af, v2, acc[r][2], 0, 0, 0);
        }
    };

    for (int T = 0; T < 32; T += 2) {
        dostep(ma, ba0, ba1, ba2);
        if (T + 2 < 32) {
            const unsigned char* g2 = bptr + (size_t)(T + 2) * 24576;
            ba0 = *(const i32x4*)(g2);
            ba1 = *(const i32x4*)(g2 + 4096);
            ba2 = *(const i32x4*)(g2 + 8192);
            ma = mptr[(size_t)(T + 2) * 128];
        }
        dostep(mb, bb0, bb1, bb2);
        if (T + 3 < 32) {
            const unsigned char* g3 = bptr + (size_t)(T + 3) * 24576;
            bb0 = *(const i32x4*)(g3);
            bb1 = *(const i32x4*)(g3 + 4096);
            bb2 = *(const i32x4*)(g3 + 8192);
            mb = mptr[(size_t)(T + 3) * 128];
        }
    }

    // merge kg=1 partials into kg=0 via LDS
    __syncthreads();
    if (kg == 1) {
        unsigned char* dst = lds + cg * 12288 + lane * 192;
#pragma unroll
        for (int r = 0; r < 4; ++r)
#pragma unroll
            for (int pl = 0; pl < 3; ++pl)
                *(i32x4*)(dst + (r * 3 + pl) * 16) = acc[r][pl];
    }
    __syncthreads();
    if (kg == 0) {
        const unsigned char* s2 = lds + cg * 12288 + lane * 192;
#pragma unroll
        for (int r = 0; r < 4; ++r)
#pragma unroll
            for (int pl = 0; pl < 3; ++pl) {
                i32x4 v = *(const i32x4*)(s2 + (r * 3 + pl) * 16);
#pragma unroll
                for (int q = 0; q < 4; ++q) acc[r][pl][q] += v[q];
            }

        const int o = cg * 16 + (lane & 15);
#pragma unroll
        for (int r = 0; r < 4; ++r) {
#pragma unroll
            for (int q = 0; q < 4; ++q) {
                double S = (double)acc[r][0][q] + 256.0 * (double)acc[r][1][q]
                         + 65536.0 * (double)acc[r][2][q];     // exact integer
                int i = rt * 64 + r * 16 + (lane >> 4) * 4 + q;  // C/D row map (m89)
                size_t oi = ((size_t)b * GN + i) * FOUT + o;
                out[oi] = S < 0.0 ? 1.0f : 0.0f;
                if (fabs(S) <= 2048.0) {
                    unsigned int idx = atomicAdd(&nflag, 1u);
                    if (idx < 128) flagbuf[idx] = ((unsigned int)i << 6) | (unsigned int)o;
                }
            }
        }
    }

    // ---- in-block exact fixup (expected ~0.2 items/block) ----
    __syncthreads();
    unsigned int nf = nflag;
    if (nf > 128) nf = 128;
    for (unsigned int f = 0; f < nf; ++f) {
        unsigned int e = flagbuf[f];
        int o = e & 63;
        int i = (int)(e >> 6);
        int row16 = i & 15, r = (i >> 4) & 3;
        // 512 threads: s = tid>>3 (0..63), lg = (tid>>1)&3, hf = tid&1 -> jj in [hf*8, hf*8+8)
        int s = tid >> 3, lg = (tid >> 1) & 3, hf = tid & 1;
        unsigned long long w = tmask[((size_t)rt * 64 + s) * 64 + (lg * 16 + row16)];
        double ps = 0.0;
        const double* hwc = hW + ((size_t)b * GN + s * 64 + lg * 16) * FOUT + o;
#pragma unroll
        for (int jj = hf * 8; jj < hf * 8 + 8; ++jj) {
            if ((w >> (r * 16 + jj)) & 1ull)
                ps += hwc[(size_t)jj * FOUT];
        }
#pragma unroll
        for (int d = 32; d >= 1; d >>= 1) ps += __shfl_down(ps, d, 64);
        if (lane == 0) fred[wv] = ps;
        __syncthreads();
        if (tid == 0) {
            double tot = ((fred[0] + fred[1]) + (fred[2] + fred[3]))
                       + ((fred[4] + fred[5]) + (fred[6] + fred[7]));
            out[((size_t)b * GN + i) * FOUT + o] = tot < 0.0 ? 1.0f : 0.0f;
        }
        __syncthreads();
    }
}

extern "C" void kernel_launch(void* const* d_in, const int* in_sizes, int n_in,
                              void* d_out, int out_size, void* d_ws, size_t ws_size,
                              hipStream_t stream) {
    const float* h   = (const float*)d_in[0];   // [4,4096,128]
    const int*   adj = (const int*)d_in[1];     // [4096,4096]
    const float* W   = (const float*)d_in[2];   // [128,64]
    float* out = (float*)d_out;                 // [4,4096,64] f32

    char* ws = (char*)d_ws;
    double* hW                = (double*)ws;                          // 8 MB @ 0
    unsigned char* Bp         = (unsigned char*)(ws + 8388608);       // 3 MB @ 8M
    unsigned long long* tmask = (unsigned long long*)(ws + 12582912); // 2 MB @ 12M

    front_kernel<<<5120, 256, 0, stream>>>(adj, h, W, tmask, hW, Bp);
    gemm_kernel<<<256, 512, 0, stream>>>(Bp, tmask, hW, out);
}